// Round 5
// baseline (245.266 us; speedup 1.0000x reference)
//
#include <hip/hip_runtime.h>
#include <hip/hip_bf16.h>

typedef __attribute__((ext_vector_type(8))) short bf16x8;
typedef __attribute__((ext_vector_type(4))) float f32x4;
typedef __attribute__((ext_vector_type(16))) float f32x16;

#define Bsz 8192
#define Ksz 1024
#define Dsz 64
#define Nsz 4096  // d*d

__device__ __forceinline__ void async_load16(const void* g, void* lds) {
    __builtin_amdgcn_global_load_lds(
        (const __attribute__((address_space(1))) void*)g,
        (__attribute__((address_space(3))) void*)lds,
        16, 0, 0);
}

__device__ __forceinline__ float bf2f(unsigned short s) {
    union { unsigned u; float f; } x;
    x.u = ((unsigned)s) << 16;
    return x.f;
}

// ---------------------------------------------------------------------------
// Kernel 1: G [K=1024][N=4096] f32  ->  Gt [N=4096][K=1024] bf16 (transposed)
// ---------------------------------------------------------------------------
__global__ __launch_bounds__(256) void transpose_convert(
    const float* __restrict__ G, __hip_bfloat16* __restrict__ Gt)
{
    __shared__ float tile[64][65];
    const int t = threadIdx.x;
    const int n0 = blockIdx.x * 64;  // N tile
    const int k0 = blockIdx.y * 64;  // K tile

    for (int i = 0; i < 4; ++i) {
        int f4 = t + 256 * i;
        int row = f4 >> 4;
        int c4  = (f4 & 15) << 2;
        float4 v = *(const float4*)&G[(size_t)(k0 + row) * Nsz + n0 + c4];
        tile[row][c4 + 0] = v.x;
        tile[row][c4 + 1] = v.y;
        tile[row][c4 + 2] = v.z;
        tile[row][c4 + 3] = v.w;
    }
    __syncthreads();
    for (int i = 0; i < 4; ++i) {
        int o = t + 256 * i;
        int rowp = o >> 4;
        int c4   = (o & 15) << 2;
        union { ushort4 u; __hip_bfloat16 h[4]; } cvt;
        cvt.h[0] = __float2bfloat16(tile[c4 + 0][rowp]);
        cvt.h[1] = __float2bfloat16(tile[c4 + 1][rowp]);
        cvt.h[2] = __float2bfloat16(tile[c4 + 2][rowp]);
        cvt.h[3] = __float2bfloat16(tile[c4 + 3][rowp]);
        *(ushort4*)&Gt[(size_t)(n0 + rowp) * Ksz + k0 + c4] = cvt.u;
    }
}

// ---------------------------------------------------------------------------
// Kernel 2: weights via MFMA with split-bf16 (hi+lo) precision.
// ---------------------------------------------------------------------------
#define QSTR 72

__global__ __launch_bounds__(256) void weights_mfma(
    const float* __restrict__ q, const float* __restrict__ c,
    const float* __restrict__ bw, __hip_bfloat16* __restrict__ W)
{
    __shared__ __attribute__((aligned(16))) __hip_bfloat16 qh[128 * QSTR];
    __shared__ __attribute__((aligned(16))) __hip_bfloat16 ql[128 * QSTR];
    __shared__ __attribute__((aligned(16))) __hip_bfloat16 ch[128 * QSTR];
    __shared__ __attribute__((aligned(16))) __hip_bfloat16 cl[128 * QSTR];
    __shared__ float sqq[128];
    __shared__ float sqc[128];

    const int t  = threadIdx.x;
    const int b0 = blockIdx.x * 128;
    const int k0 = blockIdx.y * 128;

    for (int i = 0; i < 8; ++i) {
        int f4  = t + 256 * i;
        int row = f4 >> 4;
        int c4  = (f4 & 15) << 2;
        float4 v = *(const float4*)&q[(size_t)(b0 + row) * Dsz + c4];
        float4 u = *(const float4*)&c[(size_t)(k0 + row) * Dsz + c4];
        float qv[4] = {v.x, v.y, v.z, v.w};
        float cv[4] = {2.f * u.x, 2.f * u.y, 2.f * u.z, 2.f * u.w};
        union { ushort4 u4; __hip_bfloat16 h[4]; } qhh, qll, chh, cll;
        #pragma unroll
        for (int e = 0; e < 4; ++e) {
            __hip_bfloat16 hb = __float2bfloat16(qv[e]);
            qhh.h[e] = hb;
            qll.h[e] = __float2bfloat16(qv[e] - bf2f(*(unsigned short*)&hb));
            __hip_bfloat16 hc = __float2bfloat16(cv[e]);
            chh.h[e] = hc;
            cll.h[e] = __float2bfloat16(cv[e] - bf2f(*(unsigned short*)&hc));
        }
        *(ushort4*)&qh[row * QSTR + c4] = qhh.u4;
        *(ushort4*)&ql[row * QSTR + c4] = qll.u4;
        *(ushort4*)&ch[row * QSTR + c4] = chh.u4;
        *(ushort4*)&cl[row * QSTR + c4] = cll.u4;
    }
    __syncthreads();

    if (t < 128) {
        float s = 0.f;
        for (int x8 = 0; x8 < 64; x8 += 8) {
            bf16x8 h = *(const bf16x8*)&qh[t * QSTR + x8];
            bf16x8 l = *(const bf16x8*)&ql[t * QSTR + x8];
            #pragma unroll
            for (int e = 0; e < 8; ++e) {
                float v = bf2f((unsigned short)h[e]) + bf2f((unsigned short)l[e]);
                s += v * v;
            }
        }
        sqq[t] = s;
    } else {
        int r = t - 128;
        float s = 0.f;
        for (int x8 = 0; x8 < 64; x8 += 8) {
            bf16x8 h = *(const bf16x8*)&ch[r * QSTR + x8];
            bf16x8 l = *(const bf16x8*)&cl[r * QSTR + x8];
            #pragma unroll
            for (int e = 0; e < 8; ++e) {
                float v = 0.5f * (bf2f((unsigned short)h[e]) + bf2f((unsigned short)l[e]));
                s += v * v;
            }
        }
        sqc[r] = s;
    }
    __syncthreads();

    const int wave = t >> 6;
    const int lane = t & 63;
    const int wm = (wave >> 1) * 64;
    const int wn = (wave & 1) * 64;
    const int lrow = lane & 15;
    const int lk8  = (lane >> 4) << 3;

    f32x4 acc[4][4];
    for (int i = 0; i < 4; ++i)
        for (int j = 0; j < 4; ++j) acc[i][j] = (f32x4){0.f, 0.f, 0.f, 0.f};

    #pragma unroll
    for (int ks = 0; ks < 64; ks += 32) {
        bf16x8 ah[4], al[4], bh[4], bl[4];
        #pragma unroll
        for (int i = 0; i < 4; ++i) {
            int ra = (wm + i * 16 + lrow) * QSTR + ks + lk8;
            int rb = (wn + i * 16 + lrow) * QSTR + ks + lk8;
            ah[i] = *(const bf16x8*)&qh[ra];
            al[i] = *(const bf16x8*)&ql[ra];
            bh[i] = *(const bf16x8*)&ch[rb];
            bl[i] = *(const bf16x8*)&cl[rb];
        }
        #pragma unroll
        for (int i = 0; i < 4; ++i)
            #pragma unroll
            for (int j = 0; j < 4; ++j) {
                acc[i][j] = __builtin_amdgcn_mfma_f32_16x16x32_bf16(ah[i], bh[j], acc[i][j], 0, 0, 0);
                acc[i][j] = __builtin_amdgcn_mfma_f32_16x16x32_bf16(ah[i], bl[j], acc[i][j], 0, 0, 0);
                acc[i][j] = __builtin_amdgcn_mfma_f32_16x16x32_bf16(al[i], bh[j], acc[i][j], 0, 0, 0);
            }
    }

    const int crow = (lane >> 4) << 2;
    const int ccol = lane & 15;
    for (int j = 0; j < 4; ++j) {
        int k = wn + j * 16 + ccol;
        float bwv = bw[k0 + k];
        float sc  = sqc[k];
        #pragma unroll
        for (int i = 0; i < 4; ++i) {
            #pragma unroll
            for (int r = 0; r < 4; ++r) {
                int b = wm + i * 16 + crow + r;
                float d2 = fmaxf(sqq[b] + sc - acc[i][j][r], 0.f);
                W[(size_t)(b0 + b) * Ksz + (k0 + k)] = __float2bfloat16(__expf(-bwv * d2));
            }
        }
    }
}

// ---------------------------------------------------------------------------
// Kernel 3: C[M][N] = A[M][K] * Bt[N][K]^T  (bf16 in, f32 out)
// R3 staging (BK=32, 16 KB LDS, no swizzle) + 32x32x16 MFMA:
// per BK slab: 8 ds_read_b128 (same as 16x16 version) but 8 MFMAs instead
// of 16 — half the matrix-pipe issue slots, ~17% less MFMA-pipe time (m119).
// ---------------------------------------------------------------------------
#define TM 128
#define TN 128
#define BK 32

__global__ __launch_bounds__(256) void gemm_wg(
    const __hip_bfloat16* __restrict__ A,   // W  [M][K]
    const __hip_bfloat16* __restrict__ Bt,  // Gt [N][K]
    float* __restrict__ C)                  // [M][N]
{
    __shared__ __attribute__((aligned(16))) __hip_bfloat16 As[TM * BK]; // 8 KB
    __shared__ __attribute__((aligned(16))) __hip_bfloat16 Bs[TN * BK]; // 8 KB

    const int t    = threadIdx.x;
    const int wave = t >> 6;
    const int lane = t & 63;
    const int m0 = blockIdx.y * TM;
    const int n0 = blockIdx.x * TN;

    const int wm = (wave >> 1) * 64;
    const int wn = (wave & 1) * 64;
    const int l31 = lane & 31;
    const int hi8 = (lane >> 5) << 3;   // k-offset within fragment (0 or 8)

    f32x16 acc[2][2];
    #pragma unroll
    for (int i = 0; i < 2; ++i)
        #pragma unroll
        for (int j = 0; j < 2; ++j)
            #pragma unroll
            for (int r = 0; r < 16; ++r) acc[i][j][r] = 0.f;

    for (int k0 = 0; k0 < Ksz; k0 += BK) {
        __syncthreads();
        #pragma unroll
        for (int j = 0; j < 2; ++j) {
            int cb    = (wave * 2 + j) * 64;   // chunk base
            int chunk = cb + lane;
            int row   = chunk >> 2;
            int col8  = (chunk & 3) << 3;
            async_load16(A  + (size_t)(m0 + row) * Ksz + k0 + col8, &As[cb * 8]);
            async_load16(Bt + (size_t)(n0 + row) * Ksz + k0 + col8, &Bs[cb * 8]);
        }
        __syncthreads();

        #pragma unroll
        for (int ks = 0; ks < 2; ++ks) {        // two K=16 steps
            bf16x8 af[2], bfr[2];
            #pragma unroll
            for (int i = 0; i < 2; ++i) {
                af[i]  = *(const bf16x8*)&As[(wm + i * 32 + l31) * BK + ks * 16 + hi8];
                bfr[i] = *(const bf16x8*)&Bs[(wn + i * 32 + l31) * BK + ks * 16 + hi8];
            }
            #pragma unroll
            for (int i = 0; i < 2; ++i)
                #pragma unroll
                for (int j = 0; j < 2; ++j)
                    acc[i][j] = __builtin_amdgcn_mfma_f32_32x32x16_bf16(
                        af[i], bfr[j], acc[i][j], 0, 0, 0);
        }
    }

    // epilogue: 32x32 C/D layout col=lane&31, row=(reg&3)+8*(reg>>2)+4*(lane>>5)
    const int ccol  = lane & 31;
    const int rbase = (lane >> 5) << 2;
    for (int j = 0; j < 2; ++j) {
        int gn = n0 + wn + j * 32 + ccol;
        float diag = (gn % 65 == 0) ? 0.001f : 0.f;
        #pragma unroll
        for (int i = 0; i < 2; ++i) {
            #pragma unroll
            for (int r = 0; r < 16; ++r) {
                int rowt = (r & 3) + 8 * (r >> 2) + rbase;
                int gm = m0 + wm + i * 32 + rowt;
                C[(size_t)gm * Nsz + gn] = acc[i][j][r] + diag;
            }
        }
    }
}

// ---------------------------------------------------------------------------
extern "C" void kernel_launch(void* const* d_in, const int* in_sizes, int n_in,
                              void* d_out, int out_size, void* d_ws, size_t ws_size,
                              hipStream_t stream) {
    const float* q  = (const float*)d_in[0];
    const float* c  = (const float*)d_in[1];
    const float* bw = (const float*)d_in[2];
    const float* G  = (const float*)d_in[3];
    float* out = (float*)d_out;

    __hip_bfloat16* W  = (__hip_bfloat16*)d_ws;                        // 16 MB
    __hip_bfloat16* Gt = (__hip_bfloat16*)((char*)d_ws + (size_t)16 * 1024 * 1024); // 8 MB

    transpose_convert<<<dim3(Nsz / 64, Ksz / 64), 256, 0, stream>>>(G, Gt);
    weights_mfma<<<dim3(Bsz / 128, Ksz / 128), 256, 0, stream>>>(q, c, bw, W);
    gemm_wg<<<dim3(Nsz / TN, Bsz / TM), 256, 0, stream>>>(W, Gt, out);
}